// Round 1
// baseline (166.235 us; speedup 1.0000x reference)
//
#include <hip/hip_runtime.h>
#include <math.h>

#define BATCH    128
#define N_ATOMS  4096
#define NB       4095
#define NA       4094
#define NT       4093
#define FSTRIDE  184185                // floats per sample
#define ROWS     20465                 // MAX_LEN rows of 9 floats
#define CROWS    12288                 // coord elements (3*N_ATOMS)
#define BROWS    12285                 // bond elements  (3*NB)
#define AROWS    16376                 // angle elements (4*NA)
#define EPSV     1e-8f
#define THREADS  1024
#define WAVES    16
#define TPR      120                   // rows per tile (2 rows per lane)
#define NTILES   171                   // ceil(ROWS / TPR)

// 4-byte-aligned float4: VMEM multi-dword loads only need dword alignment on
// CDNA; cols 5..8 of row R are contiguous at float offset 9R+5 (mod-4 varies).
typedef float float4a __attribute__((ext_vector_type(4), aligned(4)));

// v12: ONE block per sample extracts ALL FOUR column streams in a single pass
// over F. Guarantees each cache line of F is fetched exactly once (94.3 MB
// total) instead of relying on twin-block L2 dedup (up to 170 MB demand when
// the dedup misses -- L2 is cold right after the harness's 377 MB poison
// fill). 2-deep unrolled stream loop keeps 4 KB/wave (64 KB/CU) in flight to
// cover HBM latency now that only 128 CUs carry the stream.

__global__ __launch_bounds__(THREADS, 1) void
local_energy_v12(const float* __restrict__ F,
                 const float* __restrict__ bond_type,   // 15 x 2
                 const float* __restrict__ angle_type,  // 13 x 2
                 const float* __restrict__ tor_type,    // 25 x 2
                 const int*   __restrict__ multiplicity,// 25
                 const float* __restrict__ opt_pars,    // 47
                 float*       __restrict__ out)         // B x 3
{
    __shared__ float          scc[CROWS];   // coords in row order: atom a = scc[3a+c]
    __shared__ unsigned short sbB[BROWS + 1];
    __shared__ unsigned short sbA[AROWS];
    __shared__ unsigned short sbT[ROWS + 1];
    __shared__ float sbt[30], sat[26], stt[50], smu[25];
    __shared__ float sred[WAVES * 3];
    // LDS total: 49152+24572+32752+40932+524+192 = 148124 B < 160 KiB -> 1 block/CU

    const int s   = blockIdx.x;        // sample 0..127
    const int tid = threadIdx.x;
    const int w   = tid >> 6;
    const int l   = tid & 63;
    const size_t sbase = (size_t)s * FSTRIDE;

    if (tid < 30)                      sbt[tid]       = bond_type[tid];
    else if (tid >= 32 && tid < 58)    sat[tid - 32]  = angle_type[tid - 32];
    else if (tid >= 64 && tid < 114)   stt[tid - 64]  = tor_type[tid - 64];
    else if (tid >= 128 && tid < 153)  smu[tid - 128] = (float)multiplicity[tid - 128];

    // ======== Phase A: single pass, extract all 4 columns at stream order ====
    // Row R: one dwordx4 at 9R+5 gives (coord[R], bond[R], angle[R], tor[R]).
    // Lane l owns rows TPR*t + 2l, +2l+1 of tile t; wave w owns tiles
    // {w, w+16, w+32, ...}; the loop takes two tiles per iteration so 4
    // dwordx4 loads are issued back-to-back before any extraction waits.
    for (int t = w; t < NTILES; t += 2 * WAVES) {
        const int tb  = t + WAVES;
        const int R0a = TPR * t  + 2 * l;           // even
        const int R0b = TPR * tb + 2 * l;           // even
        const bool ok0a = (R0a     < ROWS);
        const bool ok1a = (R0a + 1 < ROWS);
        const bool ok0b = (R0b     < ROWS);
        const bool ok1b = (R0b + 1 < ROWS);
        const float* pa = F + sbase + (size_t)9 * R0a + 5;
        const float* pb = F + sbase + (size_t)9 * R0b + 5;
        float4a v0a, v1a, v0b, v1b;
        if (ok0a) v0a = *(const float4a*)(pa);
        if (ok1a) v1a = *(const float4a*)(pa + 9);
        if (ok0b) v0b = *(const float4a*)(pb);
        if (ok1b) v1b = *(const float4a*)(pb + 9);

        // ---- extract tile A ----
        {
            const int R0 = R0a, R1 = R0a + 1;
            if (R1 < CROWS) {                        // CROWS even -> pairwise
                float2 c2; c2.x = v0a.x; c2.y = v1a.x;
                *(float2*)(scc + R0) = c2;
            }
            if (R1 < BROWS) {                        // BROWS odd -> tail single
                unsigned pk = (unsigned)(unsigned short)(int)v0a.y
                            | ((unsigned)(unsigned short)(int)v1a.y << 16);
                *(unsigned*)(sbB + R0) = pk;
            } else if (R0 < BROWS) {
                sbB[R0] = (unsigned short)(int)v0a.y;
            }
            if (R1 < AROWS) {                        // AROWS even -> pairwise
                unsigned pk = (unsigned)(unsigned short)(int)v0a.z
                            | ((unsigned)(unsigned short)(int)v1a.z << 16);
                *(unsigned*)(sbA + R0) = pk;
            }
            if (ok1a) {                              // ROWS odd -> tail single
                unsigned pk = (unsigned)(unsigned short)(int)v0a.w
                            | ((unsigned)(unsigned short)(int)v1a.w << 16);
                *(unsigned*)(sbT + R0) = pk;
            } else if (ok0a) {
                sbT[R0] = (unsigned short)(int)v0a.w;
            }
        }
        // ---- extract tile B ----
        {
            const int R0 = R0b, R1 = R0b + 1;
            if (R1 < CROWS) {
                float2 c2; c2.x = v0b.x; c2.y = v1b.x;
                *(float2*)(scc + R0) = c2;
            }
            if (R1 < BROWS) {
                unsigned pk = (unsigned)(unsigned short)(int)v0b.y
                            | ((unsigned)(unsigned short)(int)v1b.y << 16);
                *(unsigned*)(sbB + R0) = pk;
            } else if (R0 < BROWS) {
                sbB[R0] = (unsigned short)(int)v0b.y;
            }
            if (R1 < AROWS) {
                unsigned pk = (unsigned)(unsigned short)(int)v0b.z
                            | ((unsigned)(unsigned short)(int)v1b.z << 16);
                *(unsigned*)(sbA + R0) = pk;
            }
            if (ok1b) {
                unsigned pk = (unsigned)(unsigned short)(int)v0b.w
                            | ((unsigned)(unsigned short)(int)v1b.w << 16);
                *(unsigned*)(sbT + R0) = pk;
            } else if (ok0b) {
                sbT[R0] = (unsigned short)(int)v0b.w;
            }
        }
    }
    __syncthreads();

    // ======== Phase B: all three terms from compact LDS ========
    // Same i += THREADS striding as v11's split blocks -> identical
    // per-thread partial-sum order -> identical numerics.
    float eB = 0.f, eG = 0.f, eT = 0.f;
    for (int i = tid; i < NB; i += THREADS) {
        const int a0 = sbB[3 * i + 0];
        const int a1 = sbB[3 * i + 1];
        const int bt = sbB[3 * i + 2];
        const float dx = scc[3 * a0 + 0] - scc[3 * a1 + 0];
        const float dy = scc[3 * a0 + 1] - scc[3 * a1 + 1];
        const float dz = scc[3 * a0 + 2] - scc[3 * a1 + 2];
        const float r  = sqrtf(dx * dx + dy * dy + dz * dz + EPSV);
        const float t0 = r - sbt[bt * 2 + 1];
        eB += sbt[bt * 2 + 0] * t0 * t0;
    }
    for (int i = tid; i < NA; i += THREADS) {
        const int a0 = sbA[4 * i + 0];
        const int a1 = sbA[4 * i + 1];
        const int a2 = sbA[4 * i + 2];
        const int at = sbA[4 * i + 3];
        const float v1x = scc[3 * a0 + 0] - scc[3 * a1 + 0];
        const float v1y = scc[3 * a0 + 1] - scc[3 * a1 + 1];
        const float v1z = scc[3 * a0 + 2] - scc[3 * a1 + 2];
        const float v2x = scc[3 * a2 + 0] - scc[3 * a1 + 0];
        const float v2y = scc[3 * a2 + 1] - scc[3 * a1 + 1];
        const float v2z = scc[3 * a2 + 2] - scc[3 * a1 + 2];
        const float d12 = v1x * v2x + v1y * v2y + v1z * v2z;
        const float n1  = sqrtf(v1x * v1x + v1y * v1y + v1z * v1z + EPSV);
        const float n2  = sqrtf(v2x * v2x + v2y * v2y + v2z * v2z + EPSV);
        float cosang = d12 / (n1 * n2);
        cosang = fminf(fmaxf(cosang, -1.0f + 1e-6f), 1.0f - 1e-6f);
        const float t0 = acosf(cosang) - sat[at * 2 + 1];
        eG += sat[at * 2 + 0] * t0 * t0;
    }
    for (int i = tid; i < NT; i += THREADS) {
        const int ai = sbT[5 * i + 0];
        const int aj = sbT[5 * i + 1];
        const int ak = sbT[5 * i + 2];
        const int al = sbT[5 * i + 3];
        const int tt = sbT[5 * i + 4];
        const float b1x = scc[3*aj+0] - scc[3*ai+0];
        const float b1y = scc[3*aj+1] - scc[3*ai+1];
        const float b1z = scc[3*aj+2] - scc[3*ai+2];
        const float b2x = scc[3*ak+0] - scc[3*aj+0];
        const float b2y = scc[3*ak+1] - scc[3*aj+1];
        const float b2z = scc[3*ak+2] - scc[3*aj+2];
        const float b3x = scc[3*al+0] - scc[3*ak+0];
        const float b3y = scc[3*al+1] - scc[3*ak+1];
        const float b3z = scc[3*al+2] - scc[3*ak+2];
        const float n1x = b1y*b2z - b1z*b2y;
        const float n1y = b1z*b2x - b1x*b2z;
        const float n1z = b1x*b2y - b1y*b2x;
        const float n2x = b2y*b3z - b2z*b3y;
        const float n2y = b2z*b3x - b2x*b3z;
        const float n2z = b2x*b3y - b2y*b3x;
        const float inv = 1.0f / sqrtf(b2x*b2x + b2y*b2y + b2z*b2z + EPSV);
        const float bnx = b2x * inv, bny = b2y * inv, bnz = b2z * inv;
        const float m1x = n1y*bnz - n1z*bny;
        const float m1y = n1z*bnx - n1x*bnz;
        const float m1z = n1x*bny - n1y*bnx;
        const float phi = atan2f(m1x*n2x + m1y*n2y + m1z*n2z,
                                 n1x*n2x + n1y*n2y + n1z*n2z);
        eT += stt[tt * 2 + 0] * (1.0f + cosf(smu[tt] * phi - stt[tt * 2 + 1]));
    }

    // ======== Reduction + disjoint plain stores (no memset/atomics) ========
    for (int off = 32; off > 0; off >>= 1) {
        eB += __shfl_down(eB, off);
        eG += __shfl_down(eG, off);
        eT += __shfl_down(eT, off);
    }
    if (l == 0) {
        sred[w * 3 + 0] = eB;
        sred[w * 3 + 1] = eG;
        sred[w * 3 + 2] = eT;
    }
    __syncthreads();
    if (tid == 0) {
        float rB = 0.f, rG = 0.f, rT = 0.f;
        for (int i = 0; i < WAVES; ++i) {
            rB += sred[i * 3 + 0];
            rG += sred[i * 3 + 1];
            rT += sred[i * 3 + 2];
        }
        out[s * 3 + 0] = opt_pars[0] * rB;   // bonds
        out[s * 3 + 1] = opt_pars[1] * rG;   // angles
        out[s * 3 + 2] = opt_pars[2] * rT;   // torsions
    }
}

extern "C" void kernel_launch(void* const* d_in, const int* in_sizes, int n_in,
                              void* d_out, int out_size, void* d_ws, size_t ws_size,
                              hipStream_t stream) {
    const float* F            = (const float*)d_in[0];
    // d_in[1] = lengths (constant, unused)
    const float* bond_type    = (const float*)d_in[2];
    const float* angle_type   = (const float*)d_in[3];
    const float* tor_type     = (const float*)d_in[4];
    const int*   multiplicity = (const int*)  d_in[5];
    const float* opt_pars     = (const float*)d_in[6];
    float* out = (float*)d_out;

    // One block per sample; every out element written exactly once by plain
    // stores -> no memset / atomics required.
    local_energy_v12<<<dim3(BATCH), dim3(THREADS), 0, stream>>>(
        F, bond_type, angle_type, tor_type, multiplicity, opt_pars, out);
}

// Round 2
// 163.590 us; speedup vs baseline: 1.0162x; 1.0162x over previous
//
#include <hip/hip_runtime.h>
#include <math.h>

#define BATCH    128
#define N_ATOMS  4096
#define NB       4095
#define NA       4094
#define NT       4093
#define FSTRIDE  184185                // floats per sample
#define ROWS     20465                 // MAX_LEN rows of 9 floats
#define CROWS    12288                 // coord elements (3*N_ATOMS)
#define BROWS    12285                 // bond elements  (3*NB)
#define AROWS    16376                 // angle elements (4*NA)
#define EPSV     1e-8f
#define THREADS  1024
#define WAVES    16

// ---- staged-chunk geometry ----
#define CH_ROWS  736                   // rows per chunk
#define SCHUNK   6624                  // floats per chunk (= 9*CH_ROWS)
#define NF4      1656                  // SCHUNK/4 float4 loads per chunk
#define NCH_P0   28                    // ceil(ROWS  / CH_ROWS)
#define NCH_P1   23                    // ceil(AROWS / CH_ROWS)

// 4-byte-aligned float4 for the (sample-base % 16 != 0) global stream.
typedef float float4a __attribute__((ext_vector_type(4), aligned(4)));
typedef float float4w __attribute__((ext_vector_type(4), aligned(16)));

// v13: contiguous-load + LDS-stage + stride-9 extract.
// v11's per-row dwordx4 gathers (72 B lane stride) give ZERO inter-lane
// coalescing: each wave-load touches 64+ cache lines and the per-line TCP
// processing rate caps the stream at ~2.2 TB/s (v12 A/B showed the kernel is
// per-CU-issue-bound, not HBM-bound). v13 streams the raw bytes contiguously
// (1 KiB/wave-load), stages 736-row chunks in double-buffered LDS, and
// extracts cols 5..8 with stride-9 LDS reads (odd stride -> only the free
// 2-way lane aliasing). Pipeline keeps 2 chunks in flight across RAW
// s_barrier + lgkmcnt(0) (no vmcnt drain -- __syncthreads would re-expose
// HBM latency every chunk). Twin split + XCD pairing (L2 dedup) as v11.

__global__ __launch_bounds__(THREADS, 1) void
local_energy_v13(const float* __restrict__ F,
                 const float* __restrict__ bond_type,   // 15 x 2
                 const float* __restrict__ angle_type,  // 13 x 2
                 const float* __restrict__ tor_type,    // 25 x 2
                 const int*   __restrict__ multiplicity,// 25
                 const float* __restrict__ opt_pars,    // 47
                 float*       __restrict__ out)         // B x 3
{
    __shared__ float scc[CROWS];                       // 48 KB, both twins
    __shared__ __align__(16) float stg[2][SCHUNK];     // 51.75 KB staging
    __shared__ union IdxU {
        struct { unsigned short bB[BROWS + 1];         // p1: bonds + angles
                 unsigned short bA[AROWS]; } q;        //     57.3 KB
        unsigned short bT[ROWS + 1];                   // p0: torsions 40.9 KB
    } u;
    __shared__ float sbt[30], sat[26], stt[50], smu[25];
    __shared__ float sred[WAVES * 2];
    // total = 49152 + 52992 + 57324 + 524 + 128 = 160120 B <= 160 KiB

    const int b   = blockIdx.x;
    const int x   = b & 7;             // XCD slot (twins share it -> L2 dedup)
    const int g   = b >> 3;            // 0..31
    const int s   = (g & 15) * 8 + x;  // sample 0..127
    const int p   = g >> 4;            // 0: torsions   1: bonds + angles
    const int tid = threadIdx.x;
    const int w   = tid >> 6;
    const int l   = tid & 63;
    const float* Fb = F + (size_t)s * FSTRIDE;

    if (tid < 30)                      sbt[tid]       = bond_type[tid];
    else if (tid >= 32 && tid < 58)    sat[tid - 32]  = angle_type[tid - 32];
    else if (tid >= 64 && tid < 114)   stt[tid - 64]  = tor_type[tid - 64];
    else if (tid >= 128 && tid < 153)  smu[tid - 128] = (float)multiplicity[tid - 128];

    const int NCH    = p ? NCH_P1 : NCH_P0;
    const int rowLim = p ? AROWS  : ROWS;

    // Chunk regs: thread loads f4 #tid and (tid<632) f4 #(1024+tid).
    // p0's last chunk: valid floats end at FSTRIDE-1; the final dword
    // (float 184184 = last torsion slot) is carried in the tail reg.
#define LOADC(c, r) do {                                                      \
        const int _gf0 = (c) * SCHUNK + 4 * tid;                              \
        if (_gf0 + 4 <= FSTRIDE) r##a = *(const float4a*)(Fb + _gf0);         \
        if (tid < (NF4 - 1024) && _gf0 + 4096 + 4 <= FSTRIDE)                 \
            r##b = *(const float4a*)(Fb + _gf0 + 4096);                       \
        if (!p && (c) == NCH_P0 - 1 && tid == 1023) r##t = Fb[FSTRIDE - 1];   \
    } while (0)

#define WRITEC(c, buf, r) do {                                                \
        const int _gf0 = (c) * SCHUNK + 4 * tid;                              \
        if (_gf0 + 4 <= FSTRIDE) *(float4w*)&stg[buf][4 * tid] = r##a;        \
        if (tid < (NF4 - 1024) && _gf0 + 4096 + 4 <= FSTRIDE)                 \
            *(float4w*)&stg[buf][4 * tid + 4096] = r##b;                      \
        if (!p && (c) == NCH_P0 - 1 && tid == 1023) stg[buf][5336] = r##t;    \
    } while (0)

    // stride-9 LDS reads: lanes t, t+32 differ by 288 floats == 0 mod 32 ->
    // 2-way bank aliasing only (free, m136).
#define EXTRACT(c, buf) do {                                                  \
        if (tid < CH_ROWS) {                                                  \
            const int _R = (c) * CH_ROWS + tid;                               \
            if (_R < rowLim) {                                                \
                const float* _sp = &stg[buf][9 * tid + 5];                    \
                const float _v5 = _sp[0], _v6 = _sp[1];                       \
                const float _v7 = _sp[2], _v8 = _sp[3];                       \
                if (_R < CROWS) scc[_R] = _v5;                                \
                if (p) {                                                      \
                    if (_R < BROWS) u.q.bB[_R] = (unsigned short)(int)_v6;    \
                    u.q.bA[_R] = (unsigned short)(int)_v7;                    \
                } else {                                                      \
                    u.bT[_R] = (unsigned short)(int)_v8;                      \
                }                                                             \
            }                                                                 \
        }                                                                     \
    } while (0)

    // Raw barrier: lgkmcnt(0) makes this wave's ds ops visible; NO vmcnt
    // (in-flight chunk loads cross the barrier -- T3/T4). sched_barrier(0)
    // pins ds ops on both sides (rule #18: scheduler ignores bare asm waits).
#define SYNC() do {                                                           \
        __builtin_amdgcn_sched_barrier(0);                                    \
        asm volatile("s_waitcnt lgkmcnt(0)");                                 \
        __builtin_amdgcn_s_barrier();                                         \
        __builtin_amdgcn_sched_barrier(0);                                    \
    } while (0)

    // ======== Phase A: pipelined stream -> stage -> extract ========
    float4a rAa, rAb, rBa, rBb;
    float rAt = 0.f, rBt = 0.f;
    (void)rAt; (void)rBt;

    LOADC(0, rA);
    WRITEC(0, 0, rA);                  // auto-vmcnt waits only chunk 0's loads
    LOADC(1, rB);                      // chunk 1 in flight across SYNC
    SYNC();

    for (int c = 0; c < NCH; c += 2) {
        // even chunk c from stg[0]; rB holds c+1 (in flight)
        if (c + 2 < NCH) LOADC(c + 2, rA);
        EXTRACT(c, 0);
        if (c + 1 < NCH) WRITEC(c + 1, 1, rB);   // auto-vmcnt counts past rA
        SYNC();
        if (c + 1 >= NCH) break;
        // odd chunk c+1 from stg[1]; rA holds c+2 (in flight)
        if (c + 3 < NCH) LOADC(c + 3, rB);
        EXTRACT(c + 1, 1);
        if (c + 2 < NCH) WRITEC(c + 2, 0, rA);
        SYNC();
    }

    // ======== Phase B: compute from compact LDS (identical to v11) ========
    float eA = 0.f, eB = 0.f;          // p0: eA=tor | p1: eA=bond, eB=angle
    if (p) {
        for (int i = tid; i < NB; i += THREADS) {
            const int a0 = u.q.bB[3 * i + 0];
            const int a1 = u.q.bB[3 * i + 1];
            const int bt = u.q.bB[3 * i + 2];
            const float dx = scc[3 * a0 + 0] - scc[3 * a1 + 0];
            const float dy = scc[3 * a0 + 1] - scc[3 * a1 + 1];
            const float dz = scc[3 * a0 + 2] - scc[3 * a1 + 2];
            const float r  = sqrtf(dx * dx + dy * dy + dz * dz + EPSV);
            const float t0 = r - sbt[bt * 2 + 1];
            eA += sbt[bt * 2 + 0] * t0 * t0;
        }
        for (int i = tid; i < NA; i += THREADS) {
            const int a0 = u.q.bA[4 * i + 0];
            const int a1 = u.q.bA[4 * i + 1];
            const int a2 = u.q.bA[4 * i + 2];
            const int at = u.q.bA[4 * i + 3];
            const float v1x = scc[3 * a0 + 0] - scc[3 * a1 + 0];
            const float v1y = scc[3 * a0 + 1] - scc[3 * a1 + 1];
            const float v1z = scc[3 * a0 + 2] - scc[3 * a1 + 2];
            const float v2x = scc[3 * a2 + 0] - scc[3 * a1 + 0];
            const float v2y = scc[3 * a2 + 1] - scc[3 * a1 + 1];
            const float v2z = scc[3 * a2 + 2] - scc[3 * a1 + 2];
            const float d12 = v1x * v2x + v1y * v2y + v1z * v2z;
            const float n1  = sqrtf(v1x * v1x + v1y * v1y + v1z * v1z + EPSV);
            const float n2  = sqrtf(v2x * v2x + v2y * v2y + v2z * v2z + EPSV);
            float cosang = d12 / (n1 * n2);
            cosang = fminf(fmaxf(cosang, -1.0f + 1e-6f), 1.0f - 1e-6f);
            const float t0 = acosf(cosang) - sat[at * 2 + 1];
            eB += sat[at * 2 + 0] * t0 * t0;
        }
    } else {
        for (int i = tid; i < NT; i += THREADS) {
            const int ai = u.bT[5 * i + 0];
            const int aj = u.bT[5 * i + 1];
            const int ak = u.bT[5 * i + 2];
            const int al = u.bT[5 * i + 3];
            const int tt = u.bT[5 * i + 4];
            const float b1x = scc[3*aj+0] - scc[3*ai+0];
            const float b1y = scc[3*aj+1] - scc[3*ai+1];
            const float b1z = scc[3*aj+2] - scc[3*ai+2];
            const float b2x = scc[3*ak+0] - scc[3*aj+0];
            const float b2y = scc[3*ak+1] - scc[3*aj+1];
            const float b2z = scc[3*ak+2] - scc[3*aj+2];
            const float b3x = scc[3*al+0] - scc[3*ak+0];
            const float b3y = scc[3*al+1] - scc[3*ak+1];
            const float b3z = scc[3*al+2] - scc[3*ak+2];
            const float n1x = b1y*b2z - b1z*b2y;
            const float n1y = b1z*b2x - b1x*b2z;
            const float n1z = b1x*b2y - b1y*b2x;
            const float n2x = b2y*b3z - b2z*b3y;
            const float n2y = b2z*b3x - b2x*b3z;
            const float n2z = b2x*b3y - b2y*b3x;
            const float inv = 1.0f / sqrtf(b2x*b2x + b2y*b2y + b2z*b2z + EPSV);
            const float bnx = b2x * inv, bny = b2y * inv, bnz = b2z * inv;
            const float m1x = n1y*bnz - n1z*bny;
            const float m1y = n1z*bnx - n1x*bnz;
            const float m1z = n1x*bny - n1y*bnx;
            const float phi = atan2f(m1x*n2x + m1y*n2y + m1z*n2z,
                                     n1x*n2x + n1y*n2y + n1z*n2z);
            eA += stt[tt * 2 + 0] * (1.0f + cosf(smu[tt] * phi - stt[tt * 2 + 1]));
        }
    }

    // ======== Reduction + disjoint plain stores ========
    for (int off = 32; off > 0; off >>= 1) {
        eA += __shfl_down(eA, off);
        eB += __shfl_down(eB, off);
    }
    if (l == 0) {
        sred[w * 2 + 0] = eA;
        sred[w * 2 + 1] = eB;
    }
    SYNC();
    if (tid == 0) {
        float rA = 0.f, rB = 0.f;
        for (int i = 0; i < WAVES; ++i) { rA += sred[i * 2]; rB += sred[i * 2 + 1]; }
        if (p) {
            out[s * 3 + 0] = opt_pars[0] * rA;   // bonds
            out[s * 3 + 1] = opt_pars[1] * rB;   // angles
        } else {
            out[s * 3 + 2] = opt_pars[2] * rA;   // torsions
        }
    }
#undef LOADC
#undef WRITEC
#undef EXTRACT
#undef SYNC
}

extern "C" void kernel_launch(void* const* d_in, const int* in_sizes, int n_in,
                              void* d_out, int out_size, void* d_ws, size_t ws_size,
                              hipStream_t stream) {
    const float* F            = (const float*)d_in[0];
    // d_in[1] = lengths (constant, unused)
    const float* bond_type    = (const float*)d_in[2];
    const float* angle_type   = (const float*)d_in[3];
    const float* tor_type     = (const float*)d_in[4];
    const int*   multiplicity = (const int*)  d_in[5];
    const float* opt_pars     = (const float*)d_in[6];
    float* out = (float*)d_out;

    // Twin blocks per sample (p0: torsions, p1: bonds+angles); every out
    // element written exactly once by plain stores -> no memset / atomics.
    local_energy_v13<<<dim3(BATCH * 2), dim3(THREADS), 0, stream>>>(
        F, bond_type, angle_type, tor_type, multiplicity, opt_pars, out);
}